// Round 1
// baseline (259.736 us; speedup 1.0000x reference)
//
#include <hip/hip_runtime.h>
#include <hip/hip_bf16.h>

typedef __attribute__((ext_vector_type(4))) int int4v;

#define TOKENS 8192
#define IN_F   4096
#define OUT_F  4096

// ws layout (bytes):
//   0    : double hdr[2]  (hdr[0]=mean, hdr[1]=scale)
//   16   : unsigned maxbits
//   1024 : double partials[1024]
//   16384: int8 q[TOKENS][IN_F]        (33.5 MB)
//   16384 + TOKENS*IN_F: int8 s[OUT_F][IN_F]  (16.8 MB)

__global__ void k_init(unsigned* maxbits) { *maxbits = 0u; }

__global__ __launch_bounds__(256) void k_wsum(const float4* __restrict__ w,
                                              double* __restrict__ partials) {
  __shared__ double sm[256];
  double s = 0.0;
  const float4* p = w + (size_t)blockIdx.x * 4096;
  for (int i = threadIdx.x; i < 4096; i += 256) {
    float4 v = p[i];
    s += (double)v.x + (double)v.y + (double)v.z + (double)v.w;
  }
  sm[threadIdx.x] = s;
  __syncthreads();
  for (int off = 128; off > 0; off >>= 1) {
    if (threadIdx.x < off) sm[threadIdx.x] += sm[threadIdx.x + off];
    __syncthreads();
  }
  if (threadIdx.x == 0) partials[blockIdx.x] = sm[0];
}

__global__ __launch_bounds__(256) void k_xmax(const float4* __restrict__ x,
                                              unsigned* __restrict__ maxbits) {
  float m = 0.f;
  const size_t n = (size_t)TOKENS * IN_F / 4;
  for (size_t i = (size_t)blockIdx.x * 256 + threadIdx.x; i < n;
       i += (size_t)gridDim.x * 256) {
    float4 v = x[i];
    m = fmaxf(m, fmaxf(fmaxf(fabsf(v.x), fabsf(v.y)),
                       fmaxf(fabsf(v.z), fabsf(v.w))));
  }
  __shared__ float sm[256];
  sm[threadIdx.x] = m;
  __syncthreads();
  for (int off = 128; off > 0; off >>= 1) {
    if (threadIdx.x < off) sm[threadIdx.x] = fmaxf(sm[threadIdx.x], sm[threadIdx.x + off]);
    __syncthreads();
  }
  if (threadIdx.x == 0) atomicMax(maxbits, __float_as_uint(sm[0]));
}

__global__ __launch_bounds__(256) void k_finalize(double* __restrict__ hdr,
                                                  const double* __restrict__ partials,
                                                  const unsigned* __restrict__ maxbits) {
  __shared__ double sm[256];
  double s = partials[threadIdx.x] + partials[threadIdx.x + 256] +
             partials[threadIdx.x + 512] + partials[threadIdx.x + 768];
  sm[threadIdx.x] = s;
  __syncthreads();
  for (int off = 128; off > 0; off >>= 1) {
    if (threadIdx.x < off) sm[threadIdx.x] += sm[threadIdx.x + off];
    __syncthreads();
  }
  if (threadIdx.x == 0) {
    hdr[0] = sm[0] / (double)((size_t)OUT_F * IN_F);      // mean of weight
    hdr[1] = 127.0 / (double)__uint_as_float(*maxbits);   // absmax scale
  }
}

__global__ __launch_bounds__(256) void k_quant(const float4* __restrict__ x,
                                               int* __restrict__ q,
                                               const double* __restrict__ hdr) {
  const double s = hdr[1];
  size_t i = (size_t)blockIdx.x * 256 + threadIdx.x;
  float4 v = x[i];
  int a = (int)rint(s * (double)v.x);
  int b = (int)rint(s * (double)v.y);
  int c = (int)rint(s * (double)v.z);
  int d = (int)rint(s * (double)v.w);
  q[i] = (a & 255) | ((b & 255) << 8) | ((c & 255) << 16) | ((d & 255) << 24);
}

__global__ __launch_bounds__(256) void k_tern(const float4* __restrict__ w,
                                              int* __restrict__ sgn,
                                              const double* __restrict__ hdr) {
  const double m = hdr[0];
  size_t i = (size_t)blockIdx.x * 256 + threadIdx.x;
  float4 v = w[i];
  int a = ((double)v.x > m) - ((double)v.x < m);
  int b = ((double)v.y > m) - ((double)v.y < m);
  int c = ((double)v.z > m) - ((double)v.z < m);
  int d = ((double)v.w > m) - ((double)v.w < m);
  sgn[i] = (a & 255) | ((b & 255) << 8) | ((c & 255) << 16) | ((d & 255) << 24);
}

// int8 GEMM: out[M=8192][N=4096] = q[M][K=4096] . s[N][K]^T   (both row-major, B^T form)
// 128x128 tile, BK=128, 4 waves (2x2), each wave 64x64 out via 4x4 frags of 16x16x64 i8.
// LDS tiles XOR-swizzled at 16B granularity: byte = row*128 + (koff ^ ((row&7)<<4)).
// global_load_lds writes linearly (wave base + lane*16); the SOURCE address is
// pre-swizzled so reads use the same XOR (guide rule #21).
__global__ __launch_bounds__(256) void k_gemm(const signed char* __restrict__ q,
                                              const signed char* __restrict__ s,
                                              float* __restrict__ out) {
  __shared__ signed char sA[128 * 128];
  __shared__ signed char sB[128 * 128];
  const int tid  = threadIdx.x;
  const int lane = tid & 63;
  const int wid  = tid >> 6;
  const int wr   = wid >> 1, wc = wid & 1;
  const int l15  = lane & 15, l4 = lane >> 4;
  const int bn = blockIdx.x & 31;   // 32 col tiles
  const int bm = blockIdx.x >> 5;   // 64 row tiles
  const size_t row0 = (size_t)bm * 128;
  const size_t col0 = (size_t)bn * 128;

  int4v acc[4][4];
#pragma unroll
  for (int i = 0; i < 4; ++i)
#pragma unroll
    for (int j = 0; j < 4; ++j) acc[i][j] = int4v{0, 0, 0, 0};

  for (int kt = 0; kt < 32; ++kt) {
    const int k0 = kt * 128;
    __syncthreads();  // previous compute done before overwrite
#pragma unroll
    for (int i = 0; i < 4; ++i) {
      const int idx_base = i * 256 + wid * 64;     // wave-uniform
      const int idx  = idx_base + lane;
      const int row  = idx >> 3;                   // 0..127
      const int slot = idx & 7;                    // 0..7 (16B slots)
      const int koff = ((slot ^ (row & 7)) << 4);  // pre-swizzled source
      const signed char* gA = q + (row0 + row) * IN_F + k0 + koff;
      const signed char* gB = s + (col0 + row) * IN_F + k0 + koff;
      __builtin_amdgcn_global_load_lds(
          (const __attribute__((address_space(1))) void*)gA,
          (__attribute__((address_space(3))) void*)(sA + idx_base * 16), 16, 0, 0);
      __builtin_amdgcn_global_load_lds(
          (const __attribute__((address_space(1))) void*)gB,
          (__attribute__((address_space(3))) void*)(sB + idx_base * 16), 16, 0, 0);
    }
    __syncthreads();  // vmcnt drained by barrier semantics
#pragma unroll
    for (int ks = 0; ks < 2; ++ks) {
      int4v a[4], b[4];
#pragma unroll
      for (int f = 0; f < 4; ++f) {
        const int rowA = wr * 64 + f * 16 + l15;
        const int koff = ks * 64 + l4 * 16;
        a[f] = *(const int4v*)(sA + rowA * 128 + (koff ^ ((rowA & 7) << 4)));
        const int rowB = wc * 64 + f * 16 + l15;
        b[f] = *(const int4v*)(sB + rowB * 128 + (koff ^ ((rowB & 7) << 4)));
      }
#pragma unroll
      for (int fm = 0; fm < 4; ++fm)
#pragma unroll
        for (int fn = 0; fn < 4; ++fn)
          acc[fm][fn] = __builtin_amdgcn_mfma_i32_16x16x64_i8(a[fm], b[fn], acc[fm][fn], 0, 0, 0);
    }
  }

  // epilogue: C/D mapping col = lane&15 (N), row = (lane>>4)*4 + r (M)
#pragma unroll
  for (int fm = 0; fm < 4; ++fm)
#pragma unroll
    for (int fn = 0; fn < 4; ++fn)
#pragma unroll
      for (int r = 0; r < 4; ++r) {
        const size_t rg = row0 + wr * 64 + fm * 16 + l4 * 4 + r;
        const size_t cg = col0 + wc * 64 + fn * 16 + l15;
        out[rg * OUT_F + cg] = (float)acc[fm][fn][r];
      }
}

extern "C" void kernel_launch(void* const* d_in, const int* in_sizes, int n_in,
                              void* d_out, int out_size, void* d_ws, size_t ws_size,
                              hipStream_t stream) {
  const float* x = (const float*)d_in[0];   // input  [8192][4096] f32
  const float* w = (const float*)d_in[1];   // weight [4096][4096] f32
  float* out = (float*)d_out;               // [8192][4096] f32

  char* ws = (char*)d_ws;
  double*   hdr      = (double*)ws;
  unsigned* maxbits  = (unsigned*)(ws + 16);
  double*   partials = (double*)(ws + 1024);
  signed char* qbuf  = (signed char*)(ws + 16384);
  signed char* sbuf  = (signed char*)(ws + 16384 + (size_t)TOKENS * IN_F);

  k_init<<<1, 1, 0, stream>>>(maxbits);
  k_wsum<<<1024, 256, 0, stream>>>((const float4*)w, partials);
  k_xmax<<<2048, 256, 0, stream>>>((const float4*)x, maxbits);
  k_finalize<<<1, 256, 0, stream>>>(hdr, partials, maxbits);
  k_quant<<<(TOKENS * IN_F / 4) / 256, 256, 0, stream>>>((const float4*)x, (int*)qbuf, hdr);
  k_tern<<<(OUT_F * IN_F / 4) / 256, 256, 0, stream>>>((const float4*)w, (int*)sbuf, hdr);
  k_gemm<<<(TOKENS / 128) * (OUT_F / 128), 256, 0, stream>>>(qbuf, sbuf, out);
}

// Round 2
// 251.557 us; speedup vs baseline: 1.0325x; 1.0325x over previous
//
#include <hip/hip_runtime.h>
#include <hip/hip_bf16.h>

typedef __attribute__((ext_vector_type(4))) int int4v;

#define TOKENS 8192
#define IN_F   4096
#define OUT_F  4096

// ws layout (bytes):
//   0    : double hdr[2]  (hdr[0]=mean, hdr[1]=scale)
//   16   : unsigned maxbits
//   1024 : double partials[1024]
//   16384: int8 q[TOKENS][IN_F]
//   16384 + TOKENS*IN_F: int8 s[OUT_F][IN_F]

__global__ void k_init(unsigned* maxbits) { *maxbits = 0u; }

__global__ __launch_bounds__(256) void k_wsum(const float4* __restrict__ w,
                                              double* __restrict__ partials) {
  __shared__ double sm[256];
  double s = 0.0;
  const float4* p = w + (size_t)blockIdx.x * 4096;
  for (int i = threadIdx.x; i < 4096; i += 256) {
    float4 v = p[i];
    s += (double)v.x + (double)v.y + (double)v.z + (double)v.w;
  }
  sm[threadIdx.x] = s;
  __syncthreads();
  for (int off = 128; off > 0; off >>= 1) {
    if (threadIdx.x < off) sm[threadIdx.x] += sm[threadIdx.x + off];
    __syncthreads();
  }
  if (threadIdx.x == 0) partials[blockIdx.x] = sm[0];
}

__global__ __launch_bounds__(256) void k_xmax(const float4* __restrict__ x,
                                              unsigned* __restrict__ maxbits) {
  float m = 0.f;
  const size_t n = (size_t)TOKENS * IN_F / 4;
  for (size_t i = (size_t)blockIdx.x * 256 + threadIdx.x; i < n;
       i += (size_t)gridDim.x * 256) {
    float4 v = x[i];
    m = fmaxf(m, fmaxf(fmaxf(fabsf(v.x), fabsf(v.y)),
                       fmaxf(fabsf(v.z), fabsf(v.w))));
  }
  __shared__ float sm[256];
  sm[threadIdx.x] = m;
  __syncthreads();
  for (int off = 128; off > 0; off >>= 1) {
    if (threadIdx.x < off) sm[threadIdx.x] = fmaxf(sm[threadIdx.x], sm[threadIdx.x + off]);
    __syncthreads();
  }
  if (threadIdx.x == 0) atomicMax(maxbits, __float_as_uint(sm[0]));
}

__global__ __launch_bounds__(256) void k_finalize(double* __restrict__ hdr,
                                                  const double* __restrict__ partials,
                                                  const unsigned* __restrict__ maxbits) {
  __shared__ double sm[256];
  double s = partials[threadIdx.x] + partials[threadIdx.x + 256] +
             partials[threadIdx.x + 512] + partials[threadIdx.x + 768];
  sm[threadIdx.x] = s;
  __syncthreads();
  for (int off = 128; off > 0; off >>= 1) {
    if (threadIdx.x < off) sm[threadIdx.x] += sm[threadIdx.x + off];
    __syncthreads();
  }
  if (threadIdx.x == 0) {
    hdr[0] = sm[0] / (double)((size_t)OUT_F * IN_F);      // mean of weight
    hdr[1] = 127.0 / (double)__uint_as_float(*maxbits);   // absmax scale
  }
}

__global__ __launch_bounds__(256) void k_quant(const float4* __restrict__ x,
                                               int* __restrict__ q,
                                               const double* __restrict__ hdr) {
  const double s = hdr[1];
  size_t i = (size_t)blockIdx.x * 256 + threadIdx.x;
  float4 v = x[i];
  int a = (int)rint(s * (double)v.x);
  int b = (int)rint(s * (double)v.y);
  int c = (int)rint(s * (double)v.z);
  int d = (int)rint(s * (double)v.w);
  q[i] = (a & 255) | ((b & 255) << 8) | ((c & 255) << 16) | ((d & 255) << 24);
}

__global__ __launch_bounds__(256) void k_tern(const float4* __restrict__ w,
                                              int* __restrict__ sgn,
                                              const double* __restrict__ hdr) {
  const double m = hdr[0];
  size_t i = (size_t)blockIdx.x * 256 + threadIdx.x;
  float4 v = w[i];
  int a = ((double)v.x > m) - ((double)v.x < m);
  int b = ((double)v.y > m) - ((double)v.y < m);
  int c = ((double)v.z > m) - ((double)v.z < m);
  int d = ((double)v.w > m) - ((double)v.w < m);
  sgn[i] = (a & 255) | ((b & 255) << 8) | ((c & 255) << 16) | ((d & 255) << 24);
}

// ---------------------------------------------------------------------------
// int8 GEMM, 256x256 tile, BK=64 bytes, 4-deep LDS ring, counted vmcnt,
// per-phase raw barriers + setprio (T2+T3+T4+T5), XCD swizzle (T1).
// out[M=8192][N=4096] = q[M][4096] . s[N][4096]^T
// 8 waves (2M x 4N); per-wave output 128x64 = 8x4 frags of mfma_i32_16x16x64_i8.
// LDS per tile per operand: 256 rows x 64B = 16KB; slots of 16B, slot-in-row
// XOR-swizzled with (row&3); global_load_lds dest linear, SOURCE pre-swizzled
// (rule #21), ds_read applies the same XOR -> conflict-free (8 dw/bank).
// Stage of tile kt+3 targets buf[(kt-1)&3]: all reads of it drained before
// iteration kt-1's final barrier -> safe. Wrapped prefetch index keeps
// vmcnt(8) loop-invariant (tiles kt+2,kt+3 = 8 newest; waits tile kt+1 landed).
// ---------------------------------------------------------------------------
__device__ __forceinline__ void stage2(const signed char* __restrict__ gsrc,
                                       size_t grow0, int ktile,
                                       signed char* ldsbase, int tid, int wid) {
#pragma unroll
  for (int i = 0; i < 2; ++i) {
    const int slot = i * 512 + tid;     // per-lane source slot
    const int r = slot >> 2;            // row 0..255
    const int sir = slot & 3;           // 16B slot in row
    const signed char* g = gsrc + (grow0 + (size_t)r) * IN_F +
                           (size_t)ktile * 64 + ((sir ^ (r & 3)) << 4);
    __builtin_amdgcn_global_load_lds(
        (const __attribute__((address_space(1))) void*)g,
        (__attribute__((address_space(3))) void*)(ldsbase + (i * 512 + wid * 64) * 16),
        16, 0, 0);
  }
}

__global__ __launch_bounds__(512, 2) void k_gemm(const signed char* __restrict__ q,
                                                 const signed char* __restrict__ s,
                                                 float* __restrict__ out) {
  __shared__ signed char sA[4][256 * 64];   // 64 KB
  __shared__ signed char sB[4][256 * 64];   // 64 KB
  const int tid  = threadIdx.x;
  const int lane = tid & 63;
  const int wid  = tid >> 6;     // 0..7
  const int wm   = wid >> 2;     // 0..1 -> row offset wm*128
  const int wn   = wid & 3;      // 0..3 -> col offset wn*64
  const int l15  = lane & 15, l4 = lane >> 4;

  // XCD-aware swizzle: 512 blocks, 8 XCDs, 64 blocks/XCD chunk
  const int swz = (blockIdx.x & 7) * 64 + (blockIdx.x >> 3);
  const int bm = swz >> 4;       // 0..31
  const int bn = swz & 15;       // 0..15
  const size_t row0 = (size_t)bm * 256;
  const size_t col0 = (size_t)bn * 256;

  // per-lane ds_read offset within a 16-row fragment (row = base + l15):
  const int lane_off = l15 * 64 + ((l4 ^ (l15 & 3)) << 4);

  int4v acc[8][4];
#pragma unroll
  for (int i = 0; i < 8; ++i)
#pragma unroll
    for (int j = 0; j < 4; ++j) acc[i][j] = int4v{0, 0, 0, 0};

  // prologue: stage tiles 0,1,2 into bufs 0,1,2
#pragma unroll
  for (int t = 0; t < 3; ++t) {
    stage2(q, row0, t, sA[t], tid, wid);
    stage2(s, col0, t, sB[t], tid, wid);
  }
  asm volatile("s_waitcnt vmcnt(8)" ::: "memory");   // tile 0 landed (own loads)
  __builtin_amdgcn_sched_barrier(0);
  __builtin_amdgcn_s_barrier();                      // all waves' tile 0 landed
  __builtin_amdgcn_sched_barrier(0);

  for (int kt = 0; kt < 64; ++kt) {
    const int c = kt & 3;
    const int pf   = (kt + 3) & 63;   // wrapped prefetch k-tile (uniform vmcnt)
    const int pbuf = (kt + 3) & 3;
    const signed char* bufA = sA[c];
    const signed char* bufB = sB[c];

    // ---- phase 0: read A(8) + B(0,1), stage A of kt+3, MFMA n={0,1} ----
    int4v a[8], b0, b1;
#pragma unroll
    for (int m = 0; m < 8; ++m)
      a[m] = *(const int4v*)(bufA + (wm * 128 + m * 16) * 64 + lane_off);
    b0 = *(const int4v*)(bufB + (wn * 64 + 0) * 64 + lane_off);
    b1 = *(const int4v*)(bufB + (wn * 64 + 16) * 64 + lane_off);
    stage2(q, row0, pf, sA[pbuf], tid, wid);
    __builtin_amdgcn_sched_barrier(0);
    __builtin_amdgcn_s_barrier();
    asm volatile("s_waitcnt lgkmcnt(0)" ::: "memory");
    __builtin_amdgcn_sched_barrier(0);
    __builtin_amdgcn_s_setprio(1);
#pragma unroll
    for (int m = 0; m < 8; ++m) {
      acc[m][0] = __builtin_amdgcn_mfma_i32_16x16x64_i8(a[m], b0, acc[m][0], 0, 0, 0);
      acc[m][1] = __builtin_amdgcn_mfma_i32_16x16x64_i8(a[m], b1, acc[m][1], 0, 0, 0);
    }
    __builtin_amdgcn_s_setprio(0);
    __builtin_amdgcn_sched_barrier(0);
    __builtin_amdgcn_s_barrier();

    // ---- phase 1: read B(2,3), stage B of kt+3, MFMA n={2,3} ----
    int4v b2 = *(const int4v*)(bufB + (wn * 64 + 32) * 64 + lane_off);
    int4v b3 = *(const int4v*)(bufB + (wn * 64 + 48) * 64 + lane_off);
    stage2(s, col0, pf, sB[pbuf], tid, wid);
    __builtin_amdgcn_sched_barrier(0);
    __builtin_amdgcn_s_barrier();
    asm volatile("s_waitcnt lgkmcnt(0)" ::: "memory");
    __builtin_amdgcn_sched_barrier(0);
    __builtin_amdgcn_s_setprio(1);
#pragma unroll
    for (int m = 0; m < 8; ++m) {
      acc[m][2] = __builtin_amdgcn_mfma_i32_16x16x64_i8(a[m], b2, acc[m][2], 0, 0, 0);
      acc[m][3] = __builtin_amdgcn_mfma_i32_16x16x64_i8(a[m], b3, acc[m][3], 0, 0, 0);
    }
    __builtin_amdgcn_s_setprio(0);
    // end of K-tile: ensure tile kt+1 landed everywhere before next iteration
    asm volatile("s_waitcnt vmcnt(8)" ::: "memory");
    __builtin_amdgcn_sched_barrier(0);
    __builtin_amdgcn_s_barrier();
    __builtin_amdgcn_sched_barrier(0);
  }

  // epilogue: C/D mapping col = lane&15, row = (lane>>4)*4 + r
#pragma unroll
  for (int m = 0; m < 8; ++m)
#pragma unroll
    for (int n = 0; n < 4; ++n)
#pragma unroll
      for (int r = 0; r < 4; ++r) {
        const size_t rg = row0 + wm * 128 + m * 16 + l4 * 4 + r;
        const size_t cg = col0 + wn * 64 + n * 16 + l15;
        out[rg * OUT_F + cg] = (float)acc[m][n][r];
      }
}

extern "C" void kernel_launch(void* const* d_in, const int* in_sizes, int n_in,
                              void* d_out, int out_size, void* d_ws, size_t ws_size,
                              hipStream_t stream) {
  const float* x = (const float*)d_in[0];   // input  [8192][4096] f32
  const float* w = (const float*)d_in[1];   // weight [4096][4096] f32
  float* out = (float*)d_out;               // [8192][4096] f32

  char* ws = (char*)d_ws;
  double*   hdr      = (double*)ws;
  unsigned* maxbits  = (unsigned*)(ws + 16);
  double*   partials = (double*)(ws + 1024);
  signed char* qbuf  = (signed char*)(ws + 16384);
  signed char* sbuf  = (signed char*)(ws + 16384 + (size_t)TOKENS * IN_F);

  k_init<<<1, 1, 0, stream>>>(maxbits);
  k_wsum<<<1024, 256, 0, stream>>>((const float4*)w, partials);
  k_xmax<<<2048, 256, 0, stream>>>((const float4*)x, maxbits);
  k_finalize<<<1, 256, 0, stream>>>(hdr, partials, maxbits);
  k_quant<<<(TOKENS * IN_F / 4) / 256, 256, 0, stream>>>((const float4*)x, (int*)qbuf, hdr);
  k_tern<<<(OUT_F * IN_F / 4) / 256, 256, 0, stream>>>((const float4*)w, (int*)sbuf, hdr);
  k_gemm<<<(TOKENS / 256) * (OUT_F / 256), 512, 0, stream>>>(qbuf, sbuf, out);
}

// Round 3
// 236.076 us; speedup vs baseline: 1.1002x; 1.0656x over previous
//
#include <hip/hip_runtime.h>
#include <hip/hip_bf16.h>

typedef __attribute__((ext_vector_type(4))) int int4v;

#define TOKENS 8192
#define IN_F   4096
#define OUT_F  4096

// ws layout (bytes):
//   0    : double hdr[2]  (hdr[0]=mean, hdr[1]=scale)
//   16   : unsigned maxbits
//   1024 : double partials[1024]
//   16384: int8 q[TOKENS][IN_F]
//   16384 + TOKENS*IN_F: int8 s[OUT_F][IN_F]

// wsum over weight rows; block 0 also zero-inits maxbits (k_xmax launches
// strictly after this kernel completes on the same stream).
__global__ __launch_bounds__(256) void k_wsum(const float4* __restrict__ w,
                                              double* __restrict__ partials,
                                              unsigned* __restrict__ maxbits) {
  if (blockIdx.x == 0 && threadIdx.x == 0) *maxbits = 0u;
  __shared__ double sm[256];
  double s = 0.0;
  const float4* p = w + (size_t)blockIdx.x * 4096;
  for (int i = threadIdx.x; i < 4096; i += 256) {
    float4 v = p[i];
    s += (double)v.x + (double)v.y + (double)v.z + (double)v.w;
  }
  sm[threadIdx.x] = s;
  __syncthreads();
  for (int off = 128; off > 0; off >>= 1) {
    if (threadIdx.x < off) sm[threadIdx.x] += sm[threadIdx.x + off];
    __syncthreads();
  }
  if (threadIdx.x == 0) partials[blockIdx.x] = sm[0];
}

__global__ __launch_bounds__(256) void k_xmax(const float4* __restrict__ x,
                                              unsigned* __restrict__ maxbits) {
  float m = 0.f;
  const size_t n = (size_t)TOKENS * IN_F / 4;
  for (size_t i = (size_t)blockIdx.x * 256 + threadIdx.x; i < n;
       i += (size_t)gridDim.x * 256) {
    float4 v = x[i];
    m = fmaxf(m, fmaxf(fmaxf(fabsf(v.x), fabsf(v.y)),
                       fmaxf(fabsf(v.z), fabsf(v.w))));
  }
  __shared__ float sm[256];
  sm[threadIdx.x] = m;
  __syncthreads();
  for (int off = 128; off > 0; off >>= 1) {
    if (threadIdx.x < off) sm[threadIdx.x] = fmaxf(sm[threadIdx.x], sm[threadIdx.x + off]);
    __syncthreads();
  }
  if (threadIdx.x == 0) atomicMax(maxbits, __float_as_uint(sm[0]));
}

__global__ __launch_bounds__(256) void k_finalize(double* __restrict__ hdr,
                                                  const double* __restrict__ partials,
                                                  const unsigned* __restrict__ maxbits) {
  __shared__ double sm[256];
  double s = partials[threadIdx.x] + partials[threadIdx.x + 256] +
             partials[threadIdx.x + 512] + partials[threadIdx.x + 768];
  sm[threadIdx.x] = s;
  __syncthreads();
  for (int off = 128; off > 0; off >>= 1) {
    if (threadIdx.x < off) sm[threadIdx.x] += sm[threadIdx.x + off];
    __syncthreads();
  }
  if (threadIdx.x == 0) {
    hdr[0] = sm[0] / (double)((size_t)OUT_F * IN_F);      // mean of weight
    hdr[1] = 127.0 / (double)__uint_as_float(*maxbits);   // absmax scale
  }
}

// fused: blocks [0, QB_BLK) quantize x; blocks [QB_BLK, QB_BLK+TB_BLK) ternarize w
#define QB_BLK ((TOKENS * IN_F / 4) / 256)
#define TB_BLK ((OUT_F * IN_F / 4) / 256)
__global__ __launch_bounds__(256) void k_quant_tern(const float4* __restrict__ x,
                                                    const float4* __restrict__ w,
                                                    int* __restrict__ q,
                                                    int* __restrict__ sgn,
                                                    const double* __restrict__ hdr) {
  if (blockIdx.x < QB_BLK) {
    const double s = hdr[1];
    size_t i = (size_t)blockIdx.x * 256 + threadIdx.x;
    float4 v = x[i];
    int a = (int)rint(s * (double)v.x);
    int b = (int)rint(s * (double)v.y);
    int c = (int)rint(s * (double)v.z);
    int d = (int)rint(s * (double)v.w);
    q[i] = (a & 255) | ((b & 255) << 8) | ((c & 255) << 16) | ((d & 255) << 24);
  } else {
    const double m = hdr[0];
    size_t i = (size_t)(blockIdx.x - QB_BLK) * 256 + threadIdx.x;
    float4 v = w[i];
    int a = ((double)v.x > m) - ((double)v.x < m);
    int b = ((double)v.y > m) - ((double)v.y < m);
    int c = ((double)v.z > m) - ((double)v.z < m);
    int d = ((double)v.w > m) - ((double)v.w < m);
    sgn[i] = (a & 255) | ((b & 255) << 8) | ((c & 255) << 16) | ((d & 255) << 24);
  }
}

// ---------------------------------------------------------------------------
// int8 GEMM, 256x256 tile, BK=64 bytes, 4-deep LDS ring, counted vmcnt,
// per-phase raw barriers + setprio (T2+T3+T4+T5), XCD swizzle (T1).
// LDS rows are 64B = 4 slots of 16B. Bank-quad of a slot = (row&1)*4 + pos.
// Swizzle: stored position of k-slot s in row r is  s ^ ((r>>1)&3); over 16
// consecutive rows the (parity, xor) pair covers all 8 quads exactly twice ->
// quarter-wave ds_read_b128 = 2 lanes/quad on distinct rows = conflict-free.
// Source is pre-swizzled (inverse == same XOR), LDS dest linear (rule #21);
// the permutation stays inside each 64B global row, so coalescing unchanged.
// ---------------------------------------------------------------------------
__device__ __forceinline__ void stage2(const signed char* __restrict__ gsrc,
                                       size_t grow0, int ktile,
                                       signed char* ldsbase, int tid, int wid) {
#pragma unroll
  for (int i = 0; i < 2; ++i) {
    const int slot = i * 512 + tid;     // per-lane source slot
    const int r = slot >> 2;            // row 0..255
    const int sir = slot & 3;           // stored 16B position in row
    const signed char* g = gsrc + (grow0 + (size_t)r) * IN_F +
                           (size_t)ktile * 64 + ((sir ^ ((r >> 1) & 3)) << 4);
    __builtin_amdgcn_global_load_lds(
        (const __attribute__((address_space(1))) void*)g,
        (__attribute__((address_space(3))) void*)(ldsbase + (i * 512 + wid * 64) * 16),
        16, 0, 0);
  }
}

__global__ __launch_bounds__(512, 2) void k_gemm(const signed char* __restrict__ q,
                                                 const signed char* __restrict__ s,
                                                 float* __restrict__ out) {
  __shared__ signed char sA[4][256 * 64];   // 64 KB
  __shared__ signed char sB[4][256 * 64];   // 64 KB
  const int tid  = threadIdx.x;
  const int lane = tid & 63;
  const int wid  = tid >> 6;     // 0..7
  const int wm   = wid >> 2;     // 0..1 -> row offset wm*128
  const int wn   = wid & 3;      // 0..3 -> col offset wn*64
  const int l15  = lane & 15, l4 = lane >> 4;

  // XCD-aware swizzle: 512 blocks, 8 XCDs, 64 blocks/XCD chunk
  const int swz = (blockIdx.x & 7) * 64 + (blockIdx.x >> 3);
  const int bm = swz >> 4;       // 0..31
  const int bn = swz & 15;       // 0..15
  const size_t row0 = (size_t)bm * 256;
  const size_t col0 = (size_t)bn * 256;

  // per-lane ds_read offset within a 16-row fragment (row = 16-aligned base + l15):
  const int lane_off = l15 * 64 + ((l4 ^ ((l15 >> 1) & 3)) << 4);

  int4v acc[8][4];
#pragma unroll
  for (int i = 0; i < 8; ++i)
#pragma unroll
    for (int j = 0; j < 4; ++j) acc[i][j] = int4v{0, 0, 0, 0};

  // prologue: stage tiles 0,1,2 into bufs 0,1,2
#pragma unroll
  for (int t = 0; t < 3; ++t) {
    stage2(q, row0, t, sA[t], tid, wid);
    stage2(s, col0, t, sB[t], tid, wid);
  }
  asm volatile("s_waitcnt vmcnt(8)" ::: "memory");   // tile 0 landed (own loads)
  __builtin_amdgcn_sched_barrier(0);
  __builtin_amdgcn_s_barrier();                      // all waves' tile 0 landed
  __builtin_amdgcn_sched_barrier(0);

  for (int kt = 0; kt < 64; ++kt) {
    const int c = kt & 3;
    const int pf   = (kt + 3) & 63;   // wrapped prefetch k-tile (uniform vmcnt)
    const int pbuf = (kt + 3) & 3;
    const signed char* bufA = sA[c];
    const signed char* bufB = sB[c];

    // ---- phase 0: read A(8) + B(0,1), stage A of kt+3, MFMA n={0,1} ----
    int4v a[8], b0, b1;
#pragma unroll
    for (int m = 0; m < 8; ++m)
      a[m] = *(const int4v*)(bufA + (wm * 128 + m * 16) * 64 + lane_off);
    b0 = *(const int4v*)(bufB + (wn * 64 + 0) * 64 + lane_off);
    b1 = *(const int4v*)(bufB + (wn * 64 + 16) * 64 + lane_off);
    stage2(q, row0, pf, sA[pbuf], tid, wid);
    __builtin_amdgcn_sched_barrier(0);
    __builtin_amdgcn_s_barrier();
    asm volatile("s_waitcnt lgkmcnt(0)" ::: "memory");
    __builtin_amdgcn_sched_barrier(0);
    __builtin_amdgcn_s_setprio(1);
#pragma unroll
    for (int m = 0; m < 8; ++m) {
      acc[m][0] = __builtin_amdgcn_mfma_i32_16x16x64_i8(a[m], b0, acc[m][0], 0, 0, 0);
      acc[m][1] = __builtin_amdgcn_mfma_i32_16x16x64_i8(a[m], b1, acc[m][1], 0, 0, 0);
    }
    __builtin_amdgcn_s_setprio(0);
    __builtin_amdgcn_sched_barrier(0);
    __builtin_amdgcn_s_barrier();

    // ---- phase 1: read B(2,3), stage B of kt+3, MFMA n={2,3} ----
    int4v b2 = *(const int4v*)(bufB + (wn * 64 + 32) * 64 + lane_off);
    int4v b3 = *(const int4v*)(bufB + (wn * 64 + 48) * 64 + lane_off);
    stage2(s, col0, pf, sB[pbuf], tid, wid);
    __builtin_amdgcn_sched_barrier(0);
    __builtin_amdgcn_s_barrier();
    asm volatile("s_waitcnt lgkmcnt(0)" ::: "memory");
    __builtin_amdgcn_sched_barrier(0);
    __builtin_amdgcn_s_setprio(1);
#pragma unroll
    for (int m = 0; m < 8; ++m) {
      acc[m][2] = __builtin_amdgcn_mfma_i32_16x16x64_i8(a[m], b2, acc[m][2], 0, 0, 0);
      acc[m][3] = __builtin_amdgcn_mfma_i32_16x16x64_i8(a[m], b3, acc[m][3], 0, 0, 0);
    }
    __builtin_amdgcn_s_setprio(0);
    // end of K-tile: ensure tile kt+1 landed everywhere before next iteration
    asm volatile("s_waitcnt vmcnt(8)" ::: "memory");
    __builtin_amdgcn_sched_barrier(0);
    __builtin_amdgcn_s_barrier();
    __builtin_amdgcn_sched_barrier(0);
  }

  // epilogue: C/D mapping col = lane&15, row = (lane>>4)*4 + r
#pragma unroll
  for (int m = 0; m < 8; ++m)
#pragma unroll
    for (int n = 0; n < 4; ++n)
#pragma unroll
      for (int r = 0; r < 4; ++r) {
        const size_t rg = row0 + wm * 128 + m * 16 + l4 * 4 + r;
        const size_t cg = col0 + wn * 64 + n * 16 + l15;
        out[rg * OUT_F + cg] = (float)acc[m][n][r];
      }
}

extern "C" void kernel_launch(void* const* d_in, const int* in_sizes, int n_in,
                              void* d_out, int out_size, void* d_ws, size_t ws_size,
                              hipStream_t stream) {
  const float* x = (const float*)d_in[0];   // input  [8192][4096] f32
  const float* w = (const float*)d_in[1];   // weight [4096][4096] f32
  float* out = (float*)d_out;               // [8192][4096] f32

  char* ws = (char*)d_ws;
  double*   hdr      = (double*)ws;
  unsigned* maxbits  = (unsigned*)(ws + 16);
  double*   partials = (double*)(ws + 1024);
  signed char* qbuf  = (signed char*)(ws + 16384);
  signed char* sbuf  = (signed char*)(ws + 16384 + (size_t)TOKENS * IN_F);

  k_wsum<<<1024, 256, 0, stream>>>((const float4*)w, partials, maxbits);
  k_xmax<<<2048, 256, 0, stream>>>((const float4*)x, maxbits);
  k_finalize<<<1, 256, 0, stream>>>(hdr, partials, maxbits);
  k_quant_tern<<<QB_BLK + TB_BLK, 256, 0, stream>>>((const float4*)x, (const float4*)w,
                                                    (int*)qbuf, (int*)sbuf, hdr);
  k_gemm<<<(TOKENS / 256) * (OUT_F / 256), 512, 0, stream>>>(qbuf, sbuf, out);
}

// Round 4
// 231.102 us; speedup vs baseline: 1.1239x; 1.0215x over previous
//
#include <hip/hip_runtime.h>
#include <hip/hip_bf16.h>

typedef __attribute__((ext_vector_type(4))) int int4v;

#define TOKENS 8192
#define IN_F   4096
#define OUT_F  4096

// ws layout (bytes):
//   0     : double hdr[2]  (hdr[0]=mean, hdr[1]=scale)
//   1024  : double partials[1024]      (weight sums)
//   9216  : float  xpart[1024]         (per-block |x| max)
//   16384 : int8 q[TOKENS][IN_F]
//   16384 + TOKENS*IN_F: int8 s[OUT_F][IN_F]

// fused pre-pass: blocks [0,1024) sum one weight row-block each;
// blocks [1024,2048) grid-stride max over |x|. No atomics, no init needed.
__global__ __launch_bounds__(256) void k_pre(const float4* __restrict__ w,
                                             const float4* __restrict__ x,
                                             double* __restrict__ partials,
                                             float* __restrict__ xpart) {
  if (blockIdx.x < 1024) {
    __shared__ double sm[256];
    double s = 0.0;
    const float4* p = w + (size_t)blockIdx.x * 4096;
    for (int i = threadIdx.x; i < 4096; i += 256) {
      float4 v = p[i];
      s += (double)v.x + (double)v.y + (double)v.z + (double)v.w;
    }
    sm[threadIdx.x] = s;
    __syncthreads();
    for (int off = 128; off > 0; off >>= 1) {
      if (threadIdx.x < off) sm[threadIdx.x] += sm[threadIdx.x + off];
      __syncthreads();
    }
    if (threadIdx.x == 0) partials[blockIdx.x] = sm[0];
  } else {
    const int b = blockIdx.x - 1024;
    float m = 0.f;
    const size_t n = (size_t)TOKENS * IN_F / 4;
    for (size_t i = (size_t)b * 256 + threadIdx.x; i < n; i += (size_t)1024 * 256) {
      float4 v = x[i];
      m = fmaxf(m, fmaxf(fmaxf(fabsf(v.x), fabsf(v.y)),
                         fmaxf(fabsf(v.z), fabsf(v.w))));
    }
    __shared__ float smf[256];
    smf[threadIdx.x] = m;
    __syncthreads();
    for (int off = 128; off > 0; off >>= 1) {
      if (threadIdx.x < off) smf[threadIdx.x] = fmaxf(smf[threadIdx.x], smf[threadIdx.x + off]);
      __syncthreads();
    }
    if (threadIdx.x == 0) xpart[b] = smf[0];
  }
}

__global__ __launch_bounds__(256) void k_finalize(double* __restrict__ hdr,
                                                  const double* __restrict__ partials,
                                                  const float* __restrict__ xpart) {
  __shared__ double sm[256];
  __shared__ float smf[256];
  double s = partials[threadIdx.x] + partials[threadIdx.x + 256] +
             partials[threadIdx.x + 512] + partials[threadIdx.x + 768];
  float m = fmaxf(fmaxf(xpart[threadIdx.x], xpart[threadIdx.x + 256]),
                  fmaxf(xpart[threadIdx.x + 512], xpart[threadIdx.x + 768]));
  sm[threadIdx.x] = s;
  smf[threadIdx.x] = m;
  __syncthreads();
  for (int off = 128; off > 0; off >>= 1) {
    if (threadIdx.x < off) {
      sm[threadIdx.x] += sm[threadIdx.x + off];
      smf[threadIdx.x] = fmaxf(smf[threadIdx.x], smf[threadIdx.x + off]);
    }
    __syncthreads();
  }
  if (threadIdx.x == 0) {
    hdr[0] = sm[0] / (double)((size_t)OUT_F * IN_F);   // mean of weight
    hdr[1] = 127.0 / (double)smf[0];                   // absmax scale
  }
}

// fused: blocks [0, QB_BLK) quantize x; blocks [QB_BLK, QB_BLK+TB_BLK) ternarize w
#define QB_BLK ((TOKENS * IN_F / 4) / 256)
#define TB_BLK ((OUT_F * IN_F / 4) / 256)
__global__ __launch_bounds__(256) void k_quant_tern(const float4* __restrict__ x,
                                                    const float4* __restrict__ w,
                                                    int* __restrict__ q,
                                                    int* __restrict__ sgn,
                                                    const double* __restrict__ hdr) {
  if (blockIdx.x < QB_BLK) {
    const double s = hdr[1];
    size_t i = (size_t)blockIdx.x * 256 + threadIdx.x;
    float4 v = x[i];
    int a = (int)rint(s * (double)v.x);
    int b = (int)rint(s * (double)v.y);
    int c = (int)rint(s * (double)v.z);
    int d = (int)rint(s * (double)v.w);
    q[i] = (a & 255) | ((b & 255) << 8) | ((c & 255) << 16) | ((d & 255) << 24);
  } else {
    const double m = hdr[0];
    size_t i = (size_t)(blockIdx.x - QB_BLK) * 256 + threadIdx.x;
    float4 v = w[i];
    int a = ((double)v.x > m) - ((double)v.x < m);
    int b = ((double)v.y > m) - ((double)v.y < m);
    int c = ((double)v.z > m) - ((double)v.z < m);
    int d = ((double)v.w > m) - ((double)v.w < m);
    sgn[i] = (a & 255) | ((b & 255) << 8) | ((c & 255) << 16) | ((d & 255) << 24);
  }
}

// ---------------------------------------------------------------------------
// int8 GEMM, 256x128 tile, BK=64 bytes, 2-deep LDS ring (48KB -> 2 blocks/CU),
// 8 waves as 4M x 2N, per-wave 64x64 out (acc[4][4], ~120 regs -> 4 waves/SIMD).
// One barrier per K-tile; vmcnt(0) drain covered by the other resident block.
// Swizzle: stored 16B-position of k-slot sr in row r is sr ^ ((r>>1)&3)
// (both-sides involution, rule #21): ds_read_b128 lands 8 lanes/bank-quad.
// ---------------------------------------------------------------------------
__device__ __forceinline__ void stageA(const signed char* __restrict__ gsrc,
                                       size_t grow0, int ktile,
                                       signed char* ldsbase, int tid, int wid) {
#pragma unroll
  for (int i = 0; i < 2; ++i) {
    const int slot = i * 512 + tid;
    const int r = slot >> 2;            // row 0..255
    const int sir = slot & 3;
    const signed char* g = gsrc + (grow0 + (size_t)r) * IN_F +
                           (size_t)ktile * 64 + ((sir ^ ((r >> 1) & 3)) << 4);
    __builtin_amdgcn_global_load_lds(
        (const __attribute__((address_space(1))) void*)g,
        (__attribute__((address_space(3))) void*)(ldsbase + (i * 512 + wid * 64) * 16),
        16, 0, 0);
  }
}

__device__ __forceinline__ void stageB(const signed char* __restrict__ gsrc,
                                       size_t grow0, int ktile,
                                       signed char* ldsbase, int tid, int wid) {
  const int r = tid >> 2;               // row 0..127
  const int sir = tid & 3;
  const signed char* g = gsrc + (grow0 + (size_t)r) * IN_F +
                         (size_t)ktile * 64 + ((sir ^ ((r >> 1) & 3)) << 4);
  __builtin_amdgcn_global_load_lds(
      (const __attribute__((address_space(1))) void*)g,
      (__attribute__((address_space(3))) void*)(ldsbase + (wid * 64) * 16),
      16, 0, 0);
}

__global__ __launch_bounds__(512, 4) void k_gemm(const signed char* __restrict__ q,
                                                 const signed char* __restrict__ s,
                                                 float* __restrict__ out) {
  __shared__ signed char sA[2][256 * 64];   // 32 KB
  __shared__ signed char sB[2][128 * 64];   // 16 KB
  const int tid  = threadIdx.x;
  const int lane = tid & 63;
  const int wid  = tid >> 6;     // 0..7
  const int wm   = wid >> 1;     // 0..3 -> row offset wm*64
  const int wn   = wid & 1;      // 0..1 -> col offset wn*64
  const int l15  = lane & 15, l4 = lane >> 4;

  // XCD-aware swizzle: 1024 blocks, 8 XCDs, 128 blocks/XCD chunk (bijective)
  const int swz = (blockIdx.x & 7) * 128 + (blockIdx.x >> 3);
  const int bm = swz >> 5;       // 0..31  (M tiles of 256)
  const int bn = swz & 31;       // 0..31  (N tiles of 128)
  const size_t row0 = (size_t)bm * 256;
  const size_t col0 = (size_t)bn * 128;

  // per-lane ds_read offset within a 16-row fragment (row = 16-aligned base + l15):
  const int lane_off = l15 * 64 + ((l4 ^ ((l15 >> 1) & 3)) << 4);

  int4v acc[4][4];
#pragma unroll
  for (int i = 0; i < 4; ++i)
#pragma unroll
    for (int j = 0; j < 4; ++j) acc[i][j] = int4v{0, 0, 0, 0};

  // prologue: stage tile 0 into buf 0
  stageA(q, row0, 0, sA[0], tid, wid);
  stageB(s, col0, 0, sB[0], tid, wid);
  asm volatile("s_waitcnt vmcnt(0)" ::: "memory");
  __builtin_amdgcn_sched_barrier(0);
  __builtin_amdgcn_s_barrier();
  __builtin_amdgcn_sched_barrier(0);

  for (int kt = 0; kt < 64; ++kt) {
    const int c = kt & 1;
    const signed char* bufA = sA[c];
    const signed char* bufB = sB[c];

    // issue next tile's staging first (latency hides under this tile's MFMAs)
    if (kt != 63) {
      stageA(q, row0, kt + 1, sA[c ^ 1], tid, wid);
      stageB(s, col0, kt + 1, sB[c ^ 1], tid, wid);
    }
    __builtin_amdgcn_sched_barrier(0);

    int4v a[4], b[4];
#pragma unroll
    for (int f = 0; f < 4; ++f)
      a[f] = *(const int4v*)(bufA + (wm * 64 + f * 16) * 64 + lane_off);
#pragma unroll
    for (int f = 0; f < 4; ++f)
      b[f] = *(const int4v*)(bufB + (wn * 64 + f * 16) * 64 + lane_off);
    asm volatile("s_waitcnt lgkmcnt(0)" ::: "memory");
    __builtin_amdgcn_sched_barrier(0);
    __builtin_amdgcn_s_setprio(1);
#pragma unroll
    for (int fm = 0; fm < 4; ++fm)
#pragma unroll
      for (int fn = 0; fn < 4; ++fn)
        acc[fm][fn] = __builtin_amdgcn_mfma_i32_16x16x64_i8(a[fm], b[fn], acc[fm][fn], 0, 0, 0);
    __builtin_amdgcn_s_setprio(0);
    __builtin_amdgcn_sched_barrier(0);
    // next tile landed (own loads), then block-wide rendezvous
    asm volatile("s_waitcnt vmcnt(0)" ::: "memory");
    __builtin_amdgcn_sched_barrier(0);
    __builtin_amdgcn_s_barrier();
    __builtin_amdgcn_sched_barrier(0);
  }

  // epilogue: C/D mapping col = lane&15, row = (lane>>4)*4 + r
#pragma unroll
  for (int fm = 0; fm < 4; ++fm)
#pragma unroll
    for (int fn = 0; fn < 4; ++fn)
#pragma unroll
      for (int r = 0; r < 4; ++r) {
        const size_t rg = row0 + wm * 64 + fm * 16 + l4 * 4 + r;
        const size_t cg = col0 + wn * 64 + fn * 16 + l15;
        out[rg * OUT_F + cg] = (float)acc[fm][fn][r];
      }
}

extern "C" void kernel_launch(void* const* d_in, const int* in_sizes, int n_in,
                              void* d_out, int out_size, void* d_ws, size_t ws_size,
                              hipStream_t stream) {
  const float* x = (const float*)d_in[0];   // input  [8192][4096] f32
  const float* w = (const float*)d_in[1];   // weight [4096][4096] f32
  float* out = (float*)d_out;               // [8192][4096] f32

  char* ws = (char*)d_ws;
  double*   hdr      = (double*)ws;
  double*   partials = (double*)(ws + 1024);
  float*    xpart    = (float*)(ws + 9216);
  signed char* qbuf  = (signed char*)(ws + 16384);
  signed char* sbuf  = (signed char*)(ws + 16384 + (size_t)TOKENS * IN_F);

  k_pre<<<2048, 256, 0, stream>>>((const float4*)w, (const float4*)x, partials, xpart);
  k_finalize<<<1, 256, 0, stream>>>(hdr, partials, xpart);
  k_quant_tern<<<QB_BLK + TB_BLK, 256, 0, stream>>>((const float4*)x, (const float4*)w,
                                                    (int*)qbuf, (int*)sbuf, hdr);
  k_gemm<<<(TOKENS / 256) * (OUT_F / 128), 512, 0, stream>>>(qbuf, sbuf, out);
}